// Round 1
// baseline (907.893 us; speedup 1.0000x reference)
//
#include <hip/hip_runtime.h>
#include <math.h>

#define N_NODESC 50000
#define N_EDGESC 800000
#define NFD 256
#define HD 64
#define QDD 128
#define TDD 32
#define NTT 64
#define NLAY 3
#define LCLAMP 6.1030340f   // atanh(1 - 1e-5)

// ---------------------------------------------------------------- setup
__global__ void k_setup(const float* __restrict__ edge_desc, const float* __restrict__ query,
                        const float* __restrict__ Wq, const float* __restrict__ bq,
                        const float* __restrict__ Ws, const float* __restrict__ bs,
                        const float* __restrict__ attn_a,
                        const float* __restrict__ Wns1, const float* __restrict__ bns1,
                        const float* __restrict__ Wes1, const float* __restrict__ bes1,
                        float* __restrict__ out_type_emb,
                        float* __restrict__ qb, float* __restrict__ qe,
                        float* __restrict__ ta3, float* __restrict__ Te) {
  __shared__ float te_l[NTT * TDD];
  __shared__ float q_l[HD];
  int t = threadIdx.x;
  if (t < HD) {
    float acc = bq[t];
    for (int k = 0; k < QDD; ++k) acc += query[k] * Wq[k * HD + t];
    q_l[t] = acc;
  }
  for (int idx = t; idx < NTT * TDD; idx += 256) {
    int ty = idx / TDD, d = idx % TDD;
    float acc = bs[d];
    for (int k = 0; k < 64; ++k) acc += edge_desc[ty * 64 + k] * Ws[k * TDD + d];
    float v = tanhf(acc);
    te_l[idx] = v;
    out_type_emb[idx] = v;
  }
  __syncthreads();
  if (t < NLAY * NTT) {
    int l = t / NTT, ty = t % NTT;
    float acc = 0.f;
    for (int d = 0; d < TDD; ++d) acc += te_l[ty * TDD + d] * attn_a[l * (2 * HD + TDD) + 2 * HD + d];
    ta3[t] = acc;
  }
  for (int idx = t; idx < NTT * HD; idx += 256) {
    int ty = idx / HD, j = idx % HD;
    float acc = 0.f;
    for (int d = 0; d < TDD; ++d) acc += te_l[ty * TDD + d] * Wes1[(2 * HD + d) * HD + j];
    Te[idx] = acc;
  }
  if (t < HD) {
    float a1 = bns1[t], a2 = bes1[t];
    for (int k = 0; k < HD; ++k) {
      a1 += q_l[k] * Wns1[(HD + k) * HD + t];
      a2 += q_l[k] * Wes1[(2 * HD + TDD + k) * HD + t];
    }
    qb[t] = a1;
    qe[t] = a2;
  }
}

// ---------------------------------------------------------------- CSR build
__global__ void k_hist(const int* __restrict__ dst, int* __restrict__ cnt) {
  int e = blockIdx.x * 256 + threadIdx.x;
  if (e < N_EDGESC) atomicAdd(&cnt[dst[e]], 1);
}

__global__ void k_scan(const int* __restrict__ cnt, int* __restrict__ row_ptr,
                       int* __restrict__ cursor) {
  const int n = N_NODESC;
  const int seg = (n + 1023) / 1024;
  int t = threadIdx.x;
  int s0 = t * seg;
  int s1 = s0 + seg; if (s1 > n) s1 = n; if (s0 > n) s0 = n;
  int sum = 0;
  for (int i = s0; i < s1; ++i) sum += cnt[i];
  int lane = t & 63, wid = t >> 6;
  int x = sum;
#pragma unroll
  for (int off = 1; off < 64; off <<= 1) {
    int y = __shfl_up(x, off, 64);
    if (lane >= off) x += y;
  }
  __shared__ int wsum[16];
  __shared__ int woff[16];
  if (lane == 63) wsum[wid] = x;
  __syncthreads();
  if (t == 0) {
    int acc = 0;
    for (int i = 0; i < 16; ++i) { woff[i] = acc; acc += wsum[i]; }
    row_ptr[n] = acc;
  }
  __syncthreads();
  int run = woff[wid] + x - sum;
  for (int i = s0; i < s1; ++i) {
    row_ptr[i] = run;
    cursor[i] = run;
    run += cnt[i];
  }
}

__global__ void k_scatter(const int* __restrict__ src, const int* __restrict__ dst,
                          const int* __restrict__ etype, int* __restrict__ cursor,
                          int* __restrict__ csr_src, int* __restrict__ csr_type) {
  int e = blockIdx.x * 256 + threadIdx.x;
  if (e < N_EDGESC) {
    int d = dst[e];
    int pos = atomicAdd(&cursor[d], 1);
    csr_src[pos] = src[e];
    csr_type[pos] = etype[e];
  }
}

// ---------------------------------------------------------------- initial projection
// ht0 = logmap0(expmap0((X @ Wn + bn) * ts)) = u * min(|u|, L)/|u|
__global__ void __launch_bounds__(256) k_proj(const float* __restrict__ A,
                                              const float* __restrict__ Wn,
                                              const float* __restrict__ bn,
                                              const float* __restrict__ ts_p,
                                              float* __restrict__ ht0) {
  __shared__ float As[64 * 68];
  __shared__ float Wl[64 * 68];
  int tid = threadIdx.x;
  int n0 = blockIdx.x * 64;
  int tr = tid >> 4, tc = tid & 15;
  float acc[4][4];
#pragma unroll
  for (int i = 0; i < 4; ++i)
#pragma unroll
    for (int j = 0; j < 4; ++j) acc[i][j] = 0.f;

  for (int kk = 0; kk < NFD; kk += 64) {
#pragma unroll
    for (int i = 0; i < 4; ++i) {
      int lin = tid + i * 256;
      int row = lin >> 4;
      int c4 = (lin & 15) * 4;
      float4 av = make_float4(0.f, 0.f, 0.f, 0.f);
      if (n0 + row < N_NODESC) av = *(const float4*)&A[(size_t)(n0 + row) * NFD + kk + c4];
      *(float4*)&As[row * 68 + c4] = av;
      *(float4*)&Wl[row * 68 + c4] = *(const float4*)&Wn[(kk + row) * HD + c4];
    }
    __syncthreads();
    for (int k = 0; k < 64; ++k) {
      float4 wv = *(const float4*)&Wl[k * 68 + tc * 4];
      float a0 = As[(tr * 4 + 0) * 68 + k];
      float a1 = As[(tr * 4 + 1) * 68 + k];
      float a2 = As[(tr * 4 + 2) * 68 + k];
      float a3 = As[(tr * 4 + 3) * 68 + k];
      acc[0][0] += a0 * wv.x; acc[0][1] += a0 * wv.y; acc[0][2] += a0 * wv.z; acc[0][3] += a0 * wv.w;
      acc[1][0] += a1 * wv.x; acc[1][1] += a1 * wv.y; acc[1][2] += a1 * wv.z; acc[1][3] += a1 * wv.w;
      acc[2][0] += a2 * wv.x; acc[2][1] += a2 * wv.y; acc[2][2] += a2 * wv.z; acc[2][3] += a2 * wv.w;
      acc[3][0] += a3 * wv.x; acc[3][1] += a3 * wv.y; acc[3][2] += a3 * wv.z; acc[3][3] += a3 * wv.w;
    }
    __syncthreads();
  }
  float ts = ts_p[0];
  float4 bnv = *(const float4*)&bn[tc * 4];
#pragma unroll
  for (int i = 0; i < 4; ++i) {
    float u0 = (acc[i][0] + bnv.x) * ts;
    float u1 = (acc[i][1] + bnv.y) * ts;
    float u2 = (acc[i][2] + bnv.z) * ts;
    float u3 = (acc[i][3] + bnv.w) * ts;
    float ss = u0 * u0 + u1 * u1 + u2 * u2 + u3 * u3;
    ss += __shfl_xor(ss, 1, 64);
    ss += __shfl_xor(ss, 2, 64);
    ss += __shfl_xor(ss, 4, 64);
    ss += __shfl_xor(ss, 8, 64);
    float nu = fmaxf(sqrtf(ss), 1e-15f);
    float sc = fminf(nu, LCLAMP) / nu;
    int n = n0 + tr * 4 + i;
    if (n < N_NODESC) {
      *(float4*)&ht0[(size_t)n * HD + tc * 4] = make_float4(u0 * sc, u1 * sc, u2 * sc, u3 * sc);
    }
  }
}

// ---------------------------------------------------------------- msg = ht @ Wmp + bmp ; p_src, p_dst
__global__ void __launch_bounds__(256) k_msg(const float* __restrict__ ht,
                                             const float* __restrict__ Wmp_l,
                                             const float* __restrict__ bmp_l,
                                             const float* __restrict__ attn_l,
                                             float* __restrict__ msg,
                                             float* __restrict__ p_src,
                                             float* __restrict__ p_dst) {
  __shared__ float hl[64 * 68];
  int t = threadIdx.x;
  int n0 = blockIdx.x * 64;
#pragma unroll
  for (int i = 0; i < 4; ++i) {
    int lin = t + i * 256;
    int row = lin >> 4;
    int c4 = (lin & 15) * 4;
    float4 v = make_float4(0.f, 0.f, 0.f, 0.f);
    if (n0 + row < N_NODESC) v = *(const float4*)&ht[(size_t)(n0 + row) * HD + c4];
    *(float4*)&hl[row * 68 + c4] = v;
  }
  __syncthreads();
  int sub = t >> 2, jq = t & 3;
  int n = n0 + sub;
  float acc[16];
#pragma unroll
  for (int u = 0; u < 16; ++u) acc[u] = bmp_l[jq * 16 + u];
  const float* hrow = &hl[sub * 68];
  for (int k = 0; k < HD; ++k) {
    float hk = hrow[k];
    const float4* wr = (const float4*)&Wmp_l[k * HD + jq * 16];
#pragma unroll
    for (int u = 0; u < 4; ++u) {
      float4 wv = wr[u];
      acc[u * 4 + 0] += hk * wv.x;
      acc[u * 4 + 1] += hk * wv.y;
      acc[u * 4 + 2] += hk * wv.z;
      acc[u * 4 + 3] += hk * wv.w;
    }
  }
  if (n < N_NODESC) {
#pragma unroll
    for (int u = 0; u < 4; ++u)
      *(float4*)&msg[(size_t)n * HD + jq * 16 + u * 4] =
          make_float4(acc[u * 4], acc[u * 4 + 1], acc[u * 4 + 2], acc[u * 4 + 3]);
    if (jq < 2) {
      const float* a = attn_l + jq * HD;
      float p = 0.f;
      for (int k = 0; k < HD; ++k) p += hrow[k] * a[k];
      if (jq == 0) p_src[n] = p; else p_dst[n] = p;
    }
  }
}

// ---------------------------------------------------------------- softmax-aggregate per node (wave/node)
__global__ void __launch_bounds__(256) k_agg(const int* __restrict__ row_ptr,
                                             const int* __restrict__ csr_src,
                                             const int* __restrict__ csr_type,
                                             const float* __restrict__ p_src,
                                             const float* __restrict__ p_dst,
                                             const float* __restrict__ ta_l,
                                             const float* __restrict__ msg,
                                             float* __restrict__ ht_out,
                                             float* __restrict__ s_buf) {
  int lane = threadIdx.x & 63;
  int n = (blockIdx.x * 256 + threadIdx.x) >> 6;
  if (n >= N_NODESC) return;
  int start = row_ptr[n], end = row_ptr[n + 1];
  float pd = p_dst[n];
  float4 acc = make_float4(0.f, 0.f, 0.f, 0.f);
  float exsum = 0.f;
  int lq = lane & 15, lg = lane >> 4;

  if (end - start <= 64) {
    int i = start + lane;
    bool valid = i < end;
    float s = -3.4e38f;
    int sidx = 0;
    if (valid) {
      sidx = csr_src[i];
      int ty = csr_type[i];
      float v = p_src[sidx] + pd + ta_l[ty];
      s = (v > 0.f) ? v : 0.2f * v;
    }
    float m = s;
#pragma unroll
    for (int off = 32; off >= 1; off >>= 1) m = fmaxf(m, __shfl_xor(m, off, 64));
    float ex = valid ? __expf(s - m) : 0.f;
    exsum = ex;
    int cnt = end - start;
    for (int it = 0; it < cnt; it += 4) {
      int el = it + lg;
      float exk = __shfl(ex, el, 64);
      int sk = __shfl(sidx, el, 64);
      if (el < cnt) {
        float4 mv = *(const float4*)&msg[(size_t)sk * HD + lq * 4];
        acc.x += exk * mv.x; acc.y += exk * mv.y; acc.z += exk * mv.z; acc.w += exk * mv.w;
      }
    }
  } else {
    float m = -3.4e38f;
    for (int base = start; base < end; base += 64) {
      int i = base + lane;
      float s = -3.4e38f;
      if (i < end) {
        int sidx = csr_src[i];
        int ty = csr_type[i];
        float v = p_src[sidx] + pd + ta_l[ty];
        s = (v > 0.f) ? v : 0.2f * v;
        s_buf[i] = s;
      }
      m = fmaxf(m, s);
    }
#pragma unroll
    for (int off = 32; off >= 1; off >>= 1) m = fmaxf(m, __shfl_xor(m, off, 64));
    for (int base = start; base < end; base += 64) {
      int i = base + lane;
      bool valid = i < end;
      float ex = 0.f;
      int sidx = 0;
      if (valid) { ex = __expf(s_buf[i] - m); sidx = csr_src[i]; }
      exsum += ex;
      int cnt = end - base; if (cnt > 64) cnt = 64;
      for (int it = 0; it < cnt; it += 4) {
        int el = it + lg;
        float exk = __shfl(ex, el, 64);
        int sk = __shfl(sidx, el, 64);
        if (el < cnt) {
          float4 mv = *(const float4*)&msg[(size_t)sk * HD + lq * 4];
          acc.x += exk * mv.x; acc.y += exk * mv.y; acc.z += exk * mv.z; acc.w += exk * mv.w;
        }
      }
    }
  }
  // combine the 4 sub-groups
  acc.x += __shfl_xor(acc.x, 16, 64); acc.y += __shfl_xor(acc.y, 16, 64);
  acc.z += __shfl_xor(acc.z, 16, 64); acc.w += __shfl_xor(acc.w, 16, 64);
  acc.x += __shfl_xor(acc.x, 32, 64); acc.y += __shfl_xor(acc.y, 32, 64);
  acc.z += __shfl_xor(acc.z, 32, 64); acc.w += __shfl_xor(acc.w, 32, 64);
#pragma unroll
  for (int off = 32; off >= 1; off >>= 1) exsum += __shfl_xor(exsum, off, 64);
  float inv = 1.f / (exsum + 1e-15f);
  float vx = fmaxf(acc.x * inv, 0.f);
  float vy = fmaxf(acc.y * inv, 0.f);
  float vz = fmaxf(acc.z * inv, 0.f);
  float vw = fmaxf(acc.w * inv, 0.f);
  float ss = vx * vx + vy * vy + vz * vz + vw * vw;
  ss += __shfl_xor(ss, 1, 64);
  ss += __shfl_xor(ss, 2, 64);
  ss += __shfl_xor(ss, 4, 64);
  ss += __shfl_xor(ss, 8, 64);
  float nu = fmaxf(sqrtf(ss), 1e-15f);
  float sc = fminf(nu, LCLAMP) / nu;
  if (lane < 16) {
    *(float4*)&ht_out[(size_t)n * HD + lane * 4] =
        make_float4(vx * sc, vy * sc, vz * sc, vw * sc);
  }
}

// ---------------------------------------------------------------- node head + h output + edge head rows
__global__ void __launch_bounds__(256) k_score(const float* __restrict__ ht,
                                               const float* __restrict__ Wns1,
                                               const float* __restrict__ Wns2,
                                               const float* __restrict__ bns2,
                                               const float* __restrict__ Wes1,
                                               const float* __restrict__ qb,
                                               float* __restrict__ node_scores,
                                               float* __restrict__ h_out,
                                               float* __restrict__ A_src,
                                               float* __restrict__ A_dst) {
  __shared__ float hl[64 * 68];
  int t = threadIdx.x;
  int n0 = blockIdx.x * 64;
#pragma unroll
  for (int i = 0; i < 4; ++i) {
    int lin = t + i * 256;
    int row = lin >> 4;
    int c4 = (lin & 15) * 4;
    float4 v = make_float4(0.f, 0.f, 0.f, 0.f);
    if (n0 + row < N_NODESC) v = *(const float4*)&ht[(size_t)(n0 + row) * HD + c4];
    *(float4*)&hl[row * 68 + c4] = v;
  }
  __syncthreads();
  int sub = t >> 2, jq = t & 3;
  int n = n0 + sub;
  float z[16], as_[16], ad_[16];
#pragma unroll
  for (int u = 0; u < 16; ++u) { z[u] = 0.f; as_[u] = 0.f; ad_[u] = 0.f; }
  const float* hrow = &hl[sub * 68];
  for (int k = 0; k < HD; ++k) {
    float hk = hrow[k];
    const float4* w1 = (const float4*)&Wns1[k * HD + jq * 16];
    const float4* e1 = (const float4*)&Wes1[k * HD + jq * 16];
    const float4* e2 = (const float4*)&Wes1[(HD + k) * HD + jq * 16];
#pragma unroll
    for (int u = 0; u < 4; ++u) {
      float4 a = w1[u], b = e1[u], c = e2[u];
      z[u * 4 + 0] += hk * a.x; z[u * 4 + 1] += hk * a.y; z[u * 4 + 2] += hk * a.z; z[u * 4 + 3] += hk * a.w;
      as_[u * 4 + 0] += hk * b.x; as_[u * 4 + 1] += hk * b.y; as_[u * 4 + 2] += hk * b.z; as_[u * 4 + 3] += hk * b.w;
      ad_[u * 4 + 0] += hk * c.x; ad_[u * 4 + 1] += hk * c.y; ad_[u * 4 + 2] += hk * c.z; ad_[u * 4 + 3] += hk * c.w;
    }
  }
  bool valid = n < N_NODESC;
  float part = 0.f, ssp = 0.f;
  if (valid) {
#pragma unroll
    for (int u = 0; u < 4; ++u) {
      *(float4*)&A_src[(size_t)n * HD + jq * 16 + u * 4] =
          make_float4(as_[u * 4], as_[u * 4 + 1], as_[u * 4 + 2], as_[u * 4 + 3]);
      *(float4*)&A_dst[(size_t)n * HD + jq * 16 + u * 4] =
          make_float4(ad_[u * 4], ad_[u * 4 + 1], ad_[u * 4 + 2], ad_[u * 4 + 3]);
    }
#pragma unroll
    for (int u = 0; u < 16; ++u) {
      float zz = fmaxf(z[u] + qb[jq * 16 + u], 0.f);
      part += zz * Wns2[jq * 16 + u];
      float hv = hrow[jq * 16 + u];
      ssp += hv * hv;
    }
  }
  part += __shfl_xor(part, 1, 64);
  part += __shfl_xor(part, 2, 64);
  ssp += __shfl_xor(ssp, 1, 64);
  ssp += __shfl_xor(ssp, 2, 64);
  if (valid) {
    float nu = fmaxf(sqrtf(ssp), 1e-15f);
    float hs = tanhf(nu) / nu;
    if (jq == 0) node_scores[n] = 1.f / (1.f + __expf(-(part + bns2[0])));
#pragma unroll
    for (int u = 0; u < 4; ++u) {
      int o = jq * 16 + u * 4;
      *(float4*)&h_out[(size_t)n * HD + o] =
          make_float4(hrow[o] * hs, hrow[o + 1] * hs, hrow[o + 2] * hs, hrow[o + 3] * hs);
    }
  }
}

// ---------------------------------------------------------------- edge scores (wave = 4 edges)
__global__ void __launch_bounds__(256) k_edge(const int* __restrict__ src,
                                              const int* __restrict__ dst,
                                              const int* __restrict__ etype,
                                              const float* __restrict__ A_src,
                                              const float* __restrict__ A_dst,
                                              const float* __restrict__ Te,
                                              const float* __restrict__ qe,
                                              const float* __restrict__ Wes2,
                                              const float* __restrict__ bes2,
                                              float* __restrict__ edge_scores) {
  int t = threadIdx.x;
  int lane = t & 63;
  int w = (blockIdx.x * 256 + t) >> 6;
  int lg = lane >> 4, lq = lane & 15;
  int e = w * 4 + lg;
  bool valid = e < N_EDGESC;
  float4 a = make_float4(0.f, 0.f, 0.f, 0.f), b = a, c = a;
  if (valid) {
    int si = src[e], di = dst[e], ti = etype[e];
    a = *(const float4*)&A_src[(size_t)si * HD + lq * 4];
    b = *(const float4*)&A_dst[(size_t)di * HD + lq * 4];
    c = *(const float4*)&Te[ti * HD + lq * 4];
  }
  float4 q4 = *(const float4*)&qe[lq * 4];
  float4 w2 = *(const float4*)&Wes2[lq * 4];
  float vx = fmaxf(a.x + b.x + c.x + q4.x, 0.f);
  float vy = fmaxf(a.y + b.y + c.y + q4.y, 0.f);
  float vz = fmaxf(a.z + b.z + c.z + q4.z, 0.f);
  float vw = fmaxf(a.w + b.w + c.w + q4.w, 0.f);
  float p = vx * w2.x + vy * w2.y + vz * w2.z + vw * w2.w;
  p += __shfl_xor(p, 1, 64);
  p += __shfl_xor(p, 2, 64);
  p += __shfl_xor(p, 4, 64);
  p += __shfl_xor(p, 8, 64);
  if (valid && lq == 0) edge_scores[e] = 1.f / (1.f + __expf(-(p + bes2[0])));
}

// ---------------------------------------------------------------- launch
extern "C" void kernel_launch(void* const* d_in, const int* in_sizes, int n_in,
                              void* d_out, int out_size, void* d_ws, size_t ws_size,
                              hipStream_t stream) {
  const float* node_features = (const float*)d_in[0];
  const float* edge_desc = (const float*)d_in[1];
  const float* query = (const float*)d_in[2];
  const float* Wn = (const float*)d_in[3];
  const float* bn = (const float*)d_in[4];
  const float* ts = (const float*)d_in[5];
  const float* Wq = (const float*)d_in[6];
  const float* bq = (const float*)d_in[7];
  const float* Ws_ = (const float*)d_in[8];
  const float* bs = (const float*)d_in[9];
  const float* attn_a = (const float*)d_in[10];
  const float* Wmp = (const float*)d_in[11];
  const float* bmp = (const float*)d_in[12];
  const float* Wns1 = (const float*)d_in[13];
  const float* bns1 = (const float*)d_in[14];
  const float* Wns2 = (const float*)d_in[15];
  const float* bns2 = (const float*)d_in[16];
  const float* Wes1 = (const float*)d_in[17];
  const float* bes1 = (const float*)d_in[18];
  const float* Wes2 = (const float*)d_in[19];
  const float* bes2 = (const float*)d_in[20];
  const int* edge_index = (const int*)d_in[21];
  const int* etype = (const int*)d_in[22];
  const int* src = edge_index;
  const int* dst = edge_index + N_EDGESC;

  float* out_ns = (float*)d_out;
  float* out_es = out_ns + N_NODESC;
  float* out_h = out_es + N_EDGESC;
  float* out_te = out_h + (size_t)N_NODESC * HD;

  char* w = (char*)d_ws;
  auto alloc = [&](size_t bytes) {
    char* p = w;
    w += (bytes + 1023) & ~(size_t)1023;
    return p;
  };
  float* ht_a = (float*)alloc((size_t)N_NODESC * HD * 4);
  float* ht_b = (float*)alloc((size_t)N_NODESC * HD * 4);
  float* msg = (float*)alloc((size_t)N_NODESC * HD * 4);
  float* p_src = (float*)alloc(N_NODESC * 4);
  float* p_dst = (float*)alloc(N_NODESC * 4);
  float* s_buf = (float*)alloc(N_EDGESC * 4);
  float* qb = (float*)alloc(HD * 4);
  float* qe = (float*)alloc(HD * 4);
  float* ta3 = (float*)alloc(NLAY * NTT * 4);
  float* Te = (float*)alloc(NTT * HD * 4);
  int* cnt = (int*)alloc(N_NODESC * 4);
  int* row_ptr = (int*)alloc((N_NODESC + 1) * 4);
  int* cursor = (int*)alloc(N_NODESC * 4);
  int* csr_src = (int*)alloc(N_EDGESC * 4);
  int* csr_type = (int*)alloc(N_EDGESC * 4);

  hipMemsetAsync(cnt, 0, N_NODESC * 4, stream);
  k_setup<<<1, 256, 0, stream>>>(edge_desc, query, Wq, bq, Ws_, bs, attn_a, Wns1, bns1,
                                 Wes1, bes1, out_te, qb, qe, ta3, Te);
  k_hist<<<N_EDGESC / 256, 256, 0, stream>>>(dst, cnt);
  k_scan<<<1, 1024, 0, stream>>>(cnt, row_ptr, cursor);
  k_scatter<<<N_EDGESC / 256, 256, 0, stream>>>(src, dst, etype, cursor, csr_src, csr_type);
  k_proj<<<(N_NODESC + 63) / 64, 256, 0, stream>>>(node_features, Wn, bn, ts, ht_a);

  float* cur = ht_a;
  float* nxt = ht_b;
  for (int l = 0; l < NLAY; ++l) {
    k_msg<<<(N_NODESC + 63) / 64, 256, 0, stream>>>(cur, Wmp + l * HD * HD, bmp + l * HD,
                                                    attn_a + l * (2 * HD + TDD), msg, p_src, p_dst);
    k_agg<<<(N_NODESC + 3) / 4, 256, 0, stream>>>(row_ptr, csr_src, csr_type, p_src, p_dst,
                                                  ta3 + l * NTT, msg, nxt, s_buf);
    float* tmp = cur; cur = nxt; nxt = tmp;
  }
  // cur = ht3; nxt and msg are free -> reuse as A_dst / A_src
  k_score<<<(N_NODESC + 63) / 64, 256, 0, stream>>>(cur, Wns1, Wns2, bns2, Wes1, qb,
                                                    out_ns, out_h, msg, nxt);
  k_edge<<<(N_EDGESC / 4 + 3) / 4, 256, 0, stream>>>(src, dst, etype, msg, nxt, Te, qe,
                                                     Wes2, bes2, out_es);
}

// Round 3
// 552.539 us; speedup vs baseline: 1.6431x; 1.6431x over previous
//
#include <hip/hip_runtime.h>
#include <math.h>

#define NN 50000
#define NE 800000
#define NFD 256
#define HD 64
#define QDD 128
#define TDD 32
#define NTT 64
#define NLAY 3
#define LCLAMP 6.1030340f   // atanh(1 - 1e-5)
#define CHUNK 1024
#define NCHUNK 49           // ceil(50000/1024)

typedef unsigned int uint;
typedef unsigned short ushort;

__device__ __forceinline__ ushort f2bf(float f) {
  uint u = __float_as_uint(f);
  uint r = (u + 0x7FFFu + ((u >> 16) & 1u)) >> 16;
  return (ushort)r;
}
__device__ __forceinline__ float bflo(uint w) { return __uint_as_float(w << 16); }
__device__ __forceinline__ float bfhi(uint w) { return __uint_as_float(w & 0xFFFF0000u); }

// ---------------------------------------------------------------- weight transposes
__global__ void k_tr(const float* __restrict__ Wn, const float* __restrict__ Wmp,
                     const float* __restrict__ Wns1, const float* __restrict__ Wes1,
                     float* __restrict__ WnT, float* __restrict__ WmpT,
                     float* __restrict__ WnsT, float* __restrict__ WesTa,
                     float* __restrict__ WesTb) {
  int i = blockIdx.x * 256 + threadIdx.x;
  if (i < 16384) {
    int j = i >> 8, k = i & 255;
    WnT[i] = Wn[k * 64 + j];
  } else if (i < 28672) {
    int r = i - 16384; int l = r >> 12; int jk = r & 4095; int j = jk >> 6, k = jk & 63;
    WmpT[r] = Wmp[l * 4096 + k * 64 + j];
  } else if (i < 32768) {
    int r = i - 28672; int j = r >> 6, k = r & 63;
    WnsT[r] = Wns1[k * 64 + j];
  } else if (i < 40960) {
    int r = i - 32768; int m = r >> 12; int jk = r & 4095; int j = jk >> 6, k = jk & 63;
    float v = Wes1[(m * 64 + k) * 64 + j];
    if (m == 0) WesTa[jk] = v; else WesTb[jk] = v;
  }
}

// ---------------------------------------------------------------- setup (small dense precomputes)
__global__ void k_setup(const float* __restrict__ edge_desc, const float* __restrict__ query,
                        const float* __restrict__ Wq, const float* __restrict__ bq,
                        const float* __restrict__ Ws, const float* __restrict__ bs,
                        const float* __restrict__ attn_a,
                        const float* __restrict__ Wns1, const float* __restrict__ bns1,
                        const float* __restrict__ Wes1, const float* __restrict__ bes1,
                        float* __restrict__ out_type_emb,
                        float* __restrict__ qb, float* __restrict__ ta3,
                        float* __restrict__ Te2) {
  __shared__ float te_l[NTT * TDD];
  __shared__ float q_l[HD];
  __shared__ float qe_l[HD];
  int t = threadIdx.x;
  if (t < HD) {
    float acc = bq[t];
    for (int k = 0; k < QDD; ++k) acc += query[k] * Wq[k * HD + t];
    q_l[t] = acc;
  }
  for (int idx = t; idx < NTT * TDD; idx += 256) {
    int ty = idx / TDD, d = idx % TDD;
    float acc = bs[d];
    for (int k = 0; k < 64; ++k) acc += edge_desc[ty * 64 + k] * Ws[k * TDD + d];
    float v = tanhf(acc);
    te_l[idx] = v;
    out_type_emb[idx] = v;
  }
  __syncthreads();
  if (t < NLAY * NTT) {
    int l = t / NTT, ty = t % NTT;
    float acc = 0.f;
    for (int d = 0; d < TDD; ++d) acc += te_l[ty * TDD + d] * attn_a[l * (2 * HD + TDD) + 2 * HD + d];
    ta3[t] = acc;
  }
  if (t < HD) {
    float a1 = bns1[t], a2 = bes1[t];
    for (int k = 0; k < HD; ++k) {
      a1 += q_l[k] * Wns1[(HD + k) * HD + t];
      a2 += q_l[k] * Wes1[(2 * HD + TDD + k) * HD + t];
    }
    qb[t] = a1;
    qe_l[t] = a2;
  }
  __syncthreads();
  for (int idx = t; idx < NTT * HD; idx += 256) {
    int ty = idx >> 6, j = idx & 63;
    float acc = qe_l[j];
    for (int d = 0; d < TDD; ++d) acc += te_l[ty * TDD + d] * Wes1[(2 * HD + d) * HD + j];
    Te2[idx] = acc;
  }
}

// ---------------------------------------------------------------- CSR build
__global__ void k_hist(const int* __restrict__ dst, int* __restrict__ cnt) {
  int e = blockIdx.x * 256 + threadIdx.x;
  if (e < NE) atomicAdd(&cnt[dst[e]], 1);
}

__global__ void k_scanA(const int* __restrict__ cnt, int* __restrict__ bsum) {
  __shared__ int ws[4];
  int t = threadIdx.x;
  int c0 = blockIdx.x * CHUNK;
  int s = 0;
#pragma unroll
  for (int it = 0; it < 4; ++it) {
    int i = c0 + it * 256 + t;
    if (i < NN) s += cnt[i];
  }
#pragma unroll
  for (int off = 1; off < 64; off <<= 1) s += __shfl_xor(s, off, 64);
  if ((t & 63) == 0) ws[t >> 6] = s;
  __syncthreads();
  if (t == 0) bsum[blockIdx.x] = ws[0] + ws[1] + ws[2] + ws[3];
}

__global__ void k_scanB(const int* __restrict__ bsum, int* __restrict__ boff,
                        int* __restrict__ row_ptr) {
  int t = threadIdx.x;  // 64 threads
  int v = (t < NCHUNK) ? bsum[t] : 0;
  int x = v;
#pragma unroll
  for (int off = 1; off < 64; off <<= 1) {
    int y = __shfl_up(x, off, 64);
    if (t >= off) x += y;
  }
  if (t < NCHUNK) boff[t] = x - v;
  if (t == 63) row_ptr[NN] = x;
}

__global__ void k_scanC(const int* __restrict__ cnt, const int* __restrict__ boff,
                        int* __restrict__ row_ptr, int* __restrict__ cursor) {
  __shared__ int wsum[4], woff_s[4];
  int t = threadIdx.x;
  int c0 = blockIdx.x * CHUNK;
  int i0 = c0 + t * 4;
  int v0 = (i0 + 0 < NN) ? cnt[i0 + 0] : 0;
  int v1 = (i0 + 1 < NN) ? cnt[i0 + 1] : 0;
  int v2 = (i0 + 2 < NN) ? cnt[i0 + 2] : 0;
  int v3 = (i0 + 3 < NN) ? cnt[i0 + 3] : 0;
  int s4 = v0 + v1 + v2 + v3;
  int lane = t & 63, wid = t >> 6;
  int x = s4;
#pragma unroll
  for (int off = 1; off < 64; off <<= 1) {
    int y = __shfl_up(x, off, 64);
    if (lane >= off) x += y;
  }
  if (lane == 63) wsum[wid] = x;
  __syncthreads();
  if (t == 0) {
    int a = 0;
    for (int i = 0; i < 4; ++i) { woff_s[i] = a; a += wsum[i]; }
  }
  __syncthreads();
  int base = boff[blockIdx.x] + woff_s[wid] + (x - s4);
  int r0 = base, r1 = base + v0, r2 = r1 + v1, r3 = r2 + v2;
  if (i0 + 0 < NN) { row_ptr[i0 + 0] = r0; cursor[i0 + 0] = r0; }
  if (i0 + 1 < NN) { row_ptr[i0 + 1] = r1; cursor[i0 + 1] = r1; }
  if (i0 + 2 < NN) { row_ptr[i0 + 2] = r2; cursor[i0 + 2] = r2; }
  if (i0 + 3 < NN) { row_ptr[i0 + 3] = r3; cursor[i0 + 3] = r3; }
}

__global__ void k_scatter(const int* __restrict__ src, const int* __restrict__ dst,
                          const int* __restrict__ etype, int* __restrict__ cursor,
                          uint* __restrict__ csr) {
  int e = blockIdx.x * 256 + threadIdx.x;
  if (e < NE) {
    int d = dst[e];
    int pos = atomicAdd(&cursor[d], 1);
    csr[pos] = (uint)src[e] | ((uint)etype[e] << 16);
  }
}

// ---------------------------------------------------------------- initial projection
__global__ void __launch_bounds__(256) k_proj(const float* __restrict__ X,
                                              const float* __restrict__ WnT,
                                              const float* __restrict__ bn,
                                              const float* __restrict__ ts_p,
                                              float* __restrict__ ht0) {
  __shared__ float st[64 * 65];
  __shared__ float ps[4][64];
  int t = threadIdx.x;
  int n0 = blockIdx.x * 64;
  int lane = t & 63;
  int wv = t >> 6;
  int jw = __builtin_amdgcn_readfirstlane(wv * 16);
  float acc[16];
#pragma unroll
  for (int u = 0; u < 16; ++u) acc[u] = 0.f;

  for (int c = 0; c < 4; ++c) {
    __syncthreads();
#pragma unroll
    for (int it = 0; it < 4; ++it) {
      int lin = t + it * 256;
      int row = lin >> 4, c4 = (lin & 15) * 4;
      float4 v = make_float4(0.f, 0.f, 0.f, 0.f);
      if (n0 + row < NN) v = *(const float4*)&X[(size_t)(n0 + row) * NFD + c * 64 + c4];
      st[row * 65 + c4 + 0] = v.x; st[row * 65 + c4 + 1] = v.y;
      st[row * 65 + c4 + 2] = v.z; st[row * 65 + c4 + 3] = v.w;
    }
    __syncthreads();
    float a[64];
#pragma unroll
    for (int k = 0; k < 64; ++k) a[k] = st[lane * 65 + k];
    const float* wb = WnT + (size_t)jw * 256 + c * 64;
#pragma unroll
    for (int u = 0; u < 16; ++u) {
      const float* wr = wb + u * 256;
      float s = acc[u];
#pragma unroll
      for (int k = 0; k < 64; ++k) s += a[k] * wr[k];
      acc[u] = s;
    }
  }
  float ts = ts_p[0];
  float ssq = 0.f;
#pragma unroll
  for (int u = 0; u < 16; ++u) {
    float v = (acc[u] + bn[jw + u]) * ts;
    acc[u] = v;
    ssq += v * v;
  }
  ps[wv][lane] = ssq;
  __syncthreads();
  float tot = ps[0][lane] + ps[1][lane] + ps[2][lane] + ps[3][lane];
  float nu = fmaxf(sqrtf(tot), 1e-15f);
  float sc = fminf(nu, LCLAMP) / nu;
#pragma unroll
  for (int u = 0; u < 16; ++u) st[lane * 65 + jw + u] = acc[u] * sc;
  __syncthreads();
#pragma unroll
  for (int it = 0; it < 4; ++it) {
    int lin = t + it * 256;
    int row = lin >> 4, c4 = (lin & 15) * 4;
    if (n0 + row < NN) {
      float4 v = make_float4(st[row * 65 + c4 + 0], st[row * 65 + c4 + 1],
                             st[row * 65 + c4 + 2], st[row * 65 + c4 + 3]);
      *(float4*)&ht0[(size_t)(n0 + row) * HD + c4] = v;
    }
  }
}

// ---------------------------------------------------------------- msg = ht @ Wmp + bmp (bf16 out); p_src/p_dst
__global__ void __launch_bounds__(256) k_msg(const float* __restrict__ ht,
                                             const float* __restrict__ WmpT_l,
                                             const float* __restrict__ bmp_l,
                                             const float* __restrict__ attn_l,
                                             ushort* __restrict__ msgbf,
                                             float* __restrict__ p_src,
                                             float* __restrict__ p_dst) {
  __shared__ float st[64 * 65];
  __shared__ float bounce[64 * 65];
  int t = threadIdx.x;
  int n0 = blockIdx.x * 64;
  int lane = t & 63;
  int wv = t >> 6;
  int jw = __builtin_amdgcn_readfirstlane(wv * 16);
#pragma unroll
  for (int it = 0; it < 4; ++it) {
    int lin = t + it * 256;
    int row = lin >> 4, c4 = (lin & 15) * 4;
    float4 v = make_float4(0.f, 0.f, 0.f, 0.f);
    if (n0 + row < NN) v = *(const float4*)&ht[(size_t)(n0 + row) * HD + c4];
    st[row * 65 + c4 + 0] = v.x; st[row * 65 + c4 + 1] = v.y;
    st[row * 65 + c4 + 2] = v.z; st[row * 65 + c4 + 3] = v.w;
  }
  __syncthreads();
  float a[64];
#pragma unroll
  for (int k = 0; k < 64; ++k) a[k] = st[lane * 65 + k];
  const float* wb = WmpT_l + jw * 64;
  for (int u = 0; u < 16; ++u) {
    const float* wr = wb + u * 64;
    float s = bmp_l[jw + u];
#pragma unroll
    for (int k = 0; k < 64; ++k) s += a[k] * wr[k];
    bounce[lane * 65 + jw + u] = s;
  }
  if (wv == 0) {
    float p1 = 0.f, p2 = 0.f;
#pragma unroll
    for (int k = 0; k < 64; ++k) { p1 += a[k] * attn_l[k]; p2 += a[k] * attn_l[64 + k]; }
    int n = n0 + lane;
    if (n < NN) { p_src[n] = p1; p_dst[n] = p2; }
  }
  __syncthreads();
#pragma unroll
  for (int it = 0; it < 2; ++it) {
    int lin = t + it * 256;
    int row = lin >> 3, c8 = (lin & 7) * 8;
    if (n0 + row < NN) {
      const float* b = &bounce[row * 65 + c8];
      uint4 o;
      o.x = (uint)f2bf(b[0]) | ((uint)f2bf(b[1]) << 16);
      o.y = (uint)f2bf(b[2]) | ((uint)f2bf(b[3]) << 16);
      o.z = (uint)f2bf(b[4]) | ((uint)f2bf(b[5]) << 16);
      o.w = (uint)f2bf(b[6]) | ((uint)f2bf(b[7]) << 16);
      *(uint4*)&msgbf[(size_t)(n0 + row) * HD + c8] = o;
    }
  }
}

// ---------------------------------------------------------------- softmax-aggregate (wave/node, 8-wide gather)
__global__ void __launch_bounds__(256) k_agg(const int* __restrict__ row_ptr,
                                             const uint* __restrict__ csr,
                                             const float* __restrict__ p_src,
                                             const float* __restrict__ p_dst,
                                             const float* __restrict__ ta_l,
                                             const ushort* __restrict__ msgbf,
                                             float* __restrict__ ht_out,
                                             float* __restrict__ s_buf) {
  int lane = threadIdx.x & 63;
  int n = (blockIdx.x * 256 + threadIdx.x) >> 6;
  if (n >= NN) return;
  int start = row_ptr[n], end = row_ptr[n + 1];
  int deg = end - start;
  float pd = p_dst[n];
  int lq = lane & 7, lg = lane >> 3;
  float acc[8];
#pragma unroll
  for (int u = 0; u < 8; ++u) acc[u] = 0.f;
  float exsum = 0.f;

  if (deg <= 64) {
    bool valid = lane < deg;
    float s = -3.4e38f;
    int sidx = 0;
    if (valid) {
      uint pk = csr[start + lane];
      sidx = (int)(pk & 0xFFFFu);
      int ty = (int)(pk >> 16);
      float v = p_src[sidx] + pd + ta_l[ty];
      s = (v > 0.f) ? v : 0.2f * v;
    }
    float m = s;
#pragma unroll
    for (int off = 32; off >= 1; off >>= 1) m = fmaxf(m, __shfl_xor(m, off, 64));
    float ex = valid ? __expf(s - m) : 0.f;
    exsum = ex;
    for (int it = 0; it < deg; it += 8) {
      int el = it + lg;
      float exk = __shfl(ex, el, 64);
      int sk = __shfl(sidx, el, 64);
      if (el < deg) {
        uint4 mv = *(const uint4*)&msgbf[(size_t)sk * HD + lq * 8];
        acc[0] += exk * bflo(mv.x); acc[1] += exk * bfhi(mv.x);
        acc[2] += exk * bflo(mv.y); acc[3] += exk * bfhi(mv.y);
        acc[4] += exk * bflo(mv.z); acc[5] += exk * bfhi(mv.z);
        acc[6] += exk * bflo(mv.w); acc[7] += exk * bfhi(mv.w);
      }
    }
  } else {
    float m = -3.4e38f;
    for (int base = start; base < end; base += 64) {
      int i = base + lane;
      float s = -3.4e38f;
      if (i < end) {
        uint pk = csr[i];
        int sidx = (int)(pk & 0xFFFFu);
        int ty = (int)(pk >> 16);
        float v = p_src[sidx] + pd + ta_l[ty];
        s = (v > 0.f) ? v : 0.2f * v;
        s_buf[i] = s;
      }
      m = fmaxf(m, s);
    }
#pragma unroll
    for (int off = 32; off >= 1; off >>= 1) m = fmaxf(m, __shfl_xor(m, off, 64));
    for (int base = start; base < end; base += 64) {
      int i = base + lane;
      if (i < end) {
        float ex = __expf(s_buf[i] - m);
        s_buf[i] = ex;
        exsum += ex;
      }
    }
    for (int it = start; it < end; it += 8) {
      int el = it + lg;
      if (el < end) {
        float exk = s_buf[el];
        int sk = (int)(csr[el] & 0xFFFFu);
        uint4 mv = *(const uint4*)&msgbf[(size_t)sk * HD + lq * 8];
        acc[0] += exk * bflo(mv.x); acc[1] += exk * bfhi(mv.x);
        acc[2] += exk * bflo(mv.y); acc[3] += exk * bfhi(mv.y);
        acc[4] += exk * bflo(mv.z); acc[5] += exk * bfhi(mv.z);
        acc[6] += exk * bflo(mv.w); acc[7] += exk * bfhi(mv.w);
      }
    }
  }
#pragma unroll
  for (int u = 0; u < 8; ++u) {
    acc[u] += __shfl_xor(acc[u], 8, 64);
    acc[u] += __shfl_xor(acc[u], 16, 64);
    acc[u] += __shfl_xor(acc[u], 32, 64);
  }
#pragma unroll
  for (int off = 32; off >= 1; off >>= 1) exsum += __shfl_xor(exsum, off, 64);
  float inv = 1.f / (exsum + 1e-15f);
  float ss = 0.f;
#pragma unroll
  for (int u = 0; u < 8; ++u) {
    float v = fmaxf(acc[u] * inv, 0.f);
    acc[u] = v;
    ss += v * v;
  }
  ss += __shfl_xor(ss, 1, 64);
  ss += __shfl_xor(ss, 2, 64);
  ss += __shfl_xor(ss, 4, 64);
  float nu = fmaxf(sqrtf(ss), 1e-15f);
  float sc = fminf(nu, LCLAMP) / nu;
  if (lane < 8) {
    *(float4*)&ht_out[(size_t)n * HD + lane * 8] =
        make_float4(acc[0] * sc, acc[1] * sc, acc[2] * sc, acc[3] * sc);
    *(float4*)&ht_out[(size_t)n * HD + lane * 8 + 4] =
        make_float4(acc[4] * sc, acc[5] * sc, acc[6] * sc, acc[7] * sc);
  }
}

// ---------------------------------------------------------------- heads: node score, h, A_src/A_dst (bf16)
__global__ void __launch_bounds__(256) k_score(const float* __restrict__ ht,
                                               const float* __restrict__ WnsT,
                                               const float* __restrict__ qb,
                                               const float* __restrict__ Wns2,
                                               const float* __restrict__ bns2,
                                               const float* __restrict__ WesTa,
                                               const float* __restrict__ WesTb,
                                               float* __restrict__ node_scores,
                                               float* __restrict__ h_out,
                                               ushort* __restrict__ Asrc,
                                               ushort* __restrict__ Adst) {
  __shared__ float st[64 * 65];
  __shared__ float bounce[64 * 65];
  __shared__ float ps[4][64];
  int t = threadIdx.x;
  int n0 = blockIdx.x * 64;
  int lane = t & 63;
  int wv = t >> 6;
  int jw = __builtin_amdgcn_readfirstlane(wv * 16);
#pragma unroll
  for (int it = 0; it < 4; ++it) {
    int lin = t + it * 256;
    int row = lin >> 4, c4 = (lin & 15) * 4;
    float4 v = make_float4(0.f, 0.f, 0.f, 0.f);
    if (n0 + row < NN) v = *(const float4*)&ht[(size_t)(n0 + row) * HD + c4];
    st[row * 65 + c4 + 0] = v.x; st[row * 65 + c4 + 1] = v.y;
    st[row * 65 + c4 + 2] = v.z; st[row * 65 + c4 + 3] = v.w;
  }
  __syncthreads();
  float a[64];
#pragma unroll
  for (int k = 0; k < 64; ++k) a[k] = st[lane * 65 + k];
  {
    const float* wb = WnsT + jw * 64;
    float part = 0.f;
    for (int u = 0; u < 16; ++u) {
      const float* wr = wb + u * 64;
      float s = 0.f;
#pragma unroll
      for (int k = 0; k < 64; ++k) s += a[k] * wr[k];
      float z = fmaxf(s + qb[jw + u], 0.f);
      part += z * Wns2[jw + u];
    }
    ps[wv][lane] = part;
  }
  {
    const float* wb = WesTa + jw * 64;
    for (int u = 0; u < 16; ++u) {
      const float* wr = wb + u * 64;
      float s = 0.f;
#pragma unroll
      for (int k = 0; k < 64; ++k) s += a[k] * wr[k];
      bounce[lane * 65 + jw + u] = s;
    }
  }
  __syncthreads();
#pragma unroll
  for (int it = 0; it < 2; ++it) {
    int lin = t + it * 256;
    int row = lin >> 3, c8 = (lin & 7) * 8;
    if (n0 + row < NN) {
      const float* b = &bounce[row * 65 + c8];
      uint4 o;
      o.x = (uint)f2bf(b[0]) | ((uint)f2bf(b[1]) << 16);
      o.y = (uint)f2bf(b[2]) | ((uint)f2bf(b[3]) << 16);
      o.z = (uint)f2bf(b[4]) | ((uint)f2bf(b[5]) << 16);
      o.w = (uint)f2bf(b[6]) | ((uint)f2bf(b[7]) << 16);
      *(uint4*)&Asrc[(size_t)(n0 + row) * HD + c8] = o;
    }
  }
  __syncthreads();
  {
    const float* wb = WesTb + jw * 64;
    for (int u = 0; u < 16; ++u) {
      const float* wr = wb + u * 64;
      float s = 0.f;
#pragma unroll
      for (int k = 0; k < 64; ++k) s += a[k] * wr[k];
      bounce[lane * 65 + jw + u] = s;
    }
  }
  __syncthreads();
#pragma unroll
  for (int it = 0; it < 2; ++it) {
    int lin = t + it * 256;
    int row = lin >> 3, c8 = (lin & 7) * 8;
    if (n0 + row < NN) {
      const float* b = &bounce[row * 65 + c8];
      uint4 o;
      o.x = (uint)f2bf(b[0]) | ((uint)f2bf(b[1]) << 16);
      o.y = (uint)f2bf(b[2]) | ((uint)f2bf(b[3]) << 16);
      o.z = (uint)f2bf(b[4]) | ((uint)f2bf(b[5]) << 16);
      o.w = (uint)f2bf(b[6]) | ((uint)f2bf(b[7]) << 16);
      *(uint4*)&Adst[(size_t)(n0 + row) * HD + c8] = o;
    }
  }
  __syncthreads();
  if (wv == 0) {
    int n = n0 + lane;
    float logit = ps[0][lane] + ps[1][lane] + ps[2][lane] + ps[3][lane] + bns2[0];
    float ssq = 0.f;
#pragma unroll
    for (int k = 0; k < 64; ++k) ssq += a[k] * a[k];
    float nu = fmaxf(sqrtf(ssq), 1e-15f);
    float hs = tanhf(nu) / nu;
    if (n < NN) node_scores[n] = 1.f / (1.f + __expf(-logit));
#pragma unroll
    for (int k = 0; k < 64; ++k) bounce[lane * 65 + k] = a[k] * hs;
  }
  __syncthreads();
#pragma unroll
  for (int it = 0; it < 4; ++it) {
    int lin = t + it * 256;
    int row = lin >> 4, c4 = (lin & 15) * 4;
    if (n0 + row < NN) {
      float4 v = make_float4(bounce[row * 65 + c4 + 0], bounce[row * 65 + c4 + 1],
                             bounce[row * 65 + c4 + 2], bounce[row * 65 + c4 + 3]);
      *(float4*)&h_out[(size_t)(n0 + row) * HD + c4] = v;
    }
  }
}

// ---------------------------------------------------------------- edge scores (8 lanes/edge, 8 edges/wave)
__global__ void __launch_bounds__(256) k_edge(const int* __restrict__ src,
                                              const int* __restrict__ dst,
                                              const int* __restrict__ etype,
                                              const ushort* __restrict__ Asrc,
                                              const ushort* __restrict__ Adst,
                                              const float* __restrict__ Te2,
                                              const float* __restrict__ Wes2,
                                              const float* __restrict__ bes2,
                                              float* __restrict__ edge_scores) {
  int t = threadIdx.x;
  int lane = t & 63;
  int lq = lane & 7, lg = lane >> 3;
  int w = (blockIdx.x * 256 + t) >> 6;
  int e = w * 8 + lg;
  float p = 0.f;
  if (e < NE) {
    int si = src[e], di = dst[e], ti = etype[e];
    uint4 av = *(const uint4*)&Asrc[(size_t)si * HD + lq * 8];
    uint4 bv = *(const uint4*)&Adst[(size_t)di * HD + lq * 8];
    const float* tp = &Te2[ti * HD + lq * 8];
    float4 t0 = *(const float4*)tp;
    float4 t1 = *(const float4*)(tp + 4);
    const float* wp = &Wes2[lq * 8];
    float4 w0 = *(const float4*)wp;
    float4 w1 = *(const float4*)(wp + 4);
    p += fmaxf(bflo(av.x) + bflo(bv.x) + t0.x, 0.f) * w0.x;
    p += fmaxf(bfhi(av.x) + bfhi(bv.x) + t0.y, 0.f) * w0.y;
    p += fmaxf(bflo(av.y) + bflo(bv.y) + t0.z, 0.f) * w0.z;
    p += fmaxf(bfhi(av.y) + bfhi(bv.y) + t0.w, 0.f) * w0.w;
    p += fmaxf(bflo(av.z) + bflo(bv.z) + t1.x, 0.f) * w1.x;
    p += fmaxf(bfhi(av.z) + bfhi(bv.z) + t1.y, 0.f) * w1.y;
    p += fmaxf(bflo(av.w) + bflo(bv.w) + t1.z, 0.f) * w1.z;
    p += fmaxf(bfhi(av.w) + bfhi(bv.w) + t1.w, 0.f) * w1.w;
  }
  p += __shfl_xor(p, 1, 64);
  p += __shfl_xor(p, 2, 64);
  p += __shfl_xor(p, 4, 64);
  if (e < NE && lq == 0) edge_scores[e] = 1.f / (1.f + __expf(-(p + bes2[0])));
}

// ---------------------------------------------------------------- launch
extern "C" void kernel_launch(void* const* d_in, const int* in_sizes, int n_in,
                              void* d_out, int out_size, void* d_ws, size_t ws_size,
                              hipStream_t stream) {
  const float* node_features = (const float*)d_in[0];
  const float* edge_desc = (const float*)d_in[1];
  const float* query = (const float*)d_in[2];
  const float* Wn = (const float*)d_in[3];
  const float* bn = (const float*)d_in[4];
  const float* ts = (const float*)d_in[5];
  const float* Wq = (const float*)d_in[6];
  const float* bq = (const float*)d_in[7];
  const float* Ws_ = (const float*)d_in[8];
  const float* bs = (const float*)d_in[9];
  const float* attn_a = (const float*)d_in[10];
  const float* Wmp = (const float*)d_in[11];
  const float* bmp = (const float*)d_in[12];
  const float* Wns1 = (const float*)d_in[13];
  const float* bns1 = (const float*)d_in[14];
  const float* Wns2 = (const float*)d_in[15];
  const float* bns2 = (const float*)d_in[16];
  const float* Wes1 = (const float*)d_in[17];
  const float* bes1 = (const float*)d_in[18];
  const float* Wes2 = (const float*)d_in[19];
  const float* bes2 = (const float*)d_in[20];
  const int* edge_index = (const int*)d_in[21];
  const int* etype = (const int*)d_in[22];
  const int* src = edge_index;
  const int* dst = edge_index + NE;

  float* out_ns = (float*)d_out;
  float* out_es = out_ns + NN;
  float* out_h = out_es + NE;
  float* out_te = out_h + (size_t)NN * HD;

  char* w = (char*)d_ws;
  auto alloc = [&](size_t bytes) {
    char* p = w;
    w += (bytes + 1023) & ~(size_t)1023;
    return p;
  };
  float* ht_a = (float*)alloc((size_t)NN * HD * 4);
  float* ht_b = (float*)alloc((size_t)NN * HD * 4);
  ushort* msgbf = (ushort*)alloc((size_t)NN * HD * 2);
  ushort* Asrc = (ushort*)alloc((size_t)NN * HD * 2);
  ushort* Adst = (ushort*)alloc((size_t)NN * HD * 2);
  float* p_src = (float*)alloc(NN * 4);
  float* p_dst = (float*)alloc(NN * 4);
  float* s_buf = (float*)alloc(NE * 4);
  float* qb = (float*)alloc(HD * 4);
  float* ta3 = (float*)alloc(NLAY * NTT * 4);
  float* Te2 = (float*)alloc(NTT * HD * 4);
  float* WnT = (float*)alloc(64 * 256 * 4);
  float* WmpT = (float*)alloc(3 * 64 * 64 * 4);
  float* WnsT = (float*)alloc(64 * 64 * 4);
  float* WesTa = (float*)alloc(64 * 64 * 4);
  float* WesTb = (float*)alloc(64 * 64 * 4);
  int* cnt = (int*)alloc(NN * 4);
  int* row_ptr = (int*)alloc((NN + 1) * 4);
  int* cursor = (int*)alloc(NN * 4);
  int* bsum = (int*)alloc(NCHUNK * 4);
  int* boff = (int*)alloc(NCHUNK * 4);
  uint* csr = (uint*)alloc(NE * 4);

  hipMemsetAsync(cnt, 0, NN * 4, stream);
  k_tr<<<160, 256, 0, stream>>>(Wn, Wmp, Wns1, Wes1, WnT, WmpT, WnsT, WesTa, WesTb);
  k_setup<<<1, 256, 0, stream>>>(edge_desc, query, Wq, bq, Ws_, bs, attn_a, Wns1, bns1,
                                 Wes1, bes1, out_te, qb, ta3, Te2);
  k_hist<<<NE / 256, 256, 0, stream>>>(dst, cnt);
  k_scanA<<<NCHUNK, 256, 0, stream>>>(cnt, bsum);
  k_scanB<<<1, 64, 0, stream>>>(bsum, boff, row_ptr);
  k_scanC<<<NCHUNK, 256, 0, stream>>>(cnt, boff, row_ptr, cursor);
  k_scatter<<<NE / 256, 256, 0, stream>>>(src, dst, etype, cursor, csr);
  k_proj<<<(NN + 63) / 64, 256, 0, stream>>>(node_features, WnT, bn, ts, ht_a);

  float* cur = ht_a;
  float* nxt = ht_b;
  for (int l = 0; l < NLAY; ++l) {
    k_msg<<<(NN + 63) / 64, 256, 0, stream>>>(cur, WmpT + l * 4096, bmp + l * HD,
                                              attn_a + l * (2 * HD + TDD), msgbf, p_src, p_dst);
    k_agg<<<(NN + 3) / 4, 256, 0, stream>>>(row_ptr, csr, p_src, p_dst, ta3 + l * NTT,
                                            msgbf, nxt, s_buf);
    float* tmp = cur; cur = nxt; nxt = tmp;
  }
  k_score<<<(NN + 63) / 64, 256, 0, stream>>>(cur, WnsT, qb, Wns2, bns2, WesTa, WesTb,
                                              out_ns, out_h, Asrc, Adst);
  // 8 edges/wave, 4 waves/block => 32 edges per block
  k_edge<<<(NE + 31) / 32, 256, 0, stream>>>(src, dst, etype, Asrc, Adst, Te2,
                                             Wes2, bes2, out_es);
}